// Round 8
// baseline (608.357 us; speedup 1.0000x reference)
//
#include <hip/hip_runtime.h>
#include <hip/hip_bf16.h>

// Problem constants (match reference)
#define NN 100000
#define EE 1000000
#define FDIM 64
#define NREL 16
#define NBASE 8
#define HN (NN * FDIM)
#define H4 (HN / 4)
#define WSZ (NREL * FDIM * FDIM)   // 65536 elements (W: 16 rels x 64x64)
#define NBIN 6250                  // dst>>4 bins: NN/16 exactly
#define KDIM 1024                  // R*FDIM contracted dim

typedef __attribute__((ext_vector_type(8))) short short8;
typedef __attribute__((ext_vector_type(4))) float f32x4;

static __device__ __forceinline__ ushort f2bf(float f) {
    __hip_bfloat16 b = __float2bfloat16(f);
    return *(ushort*)&b;
}

// ---------------- prep ----------------
// gid < NBIN+8 : zero histogram bins; gid < WSZ : WT2[o][k=r*64+d] = bf16 of the
// reinterpret-view-faithful rel weight W[r][d][o] (verified rounds 3-7):
//   W[r][d][o] = sum_b w_comp[d&15,b] * weight[(4r+(d>>4))*512 + b*64 + o]
// gid < H4 : out = relu(h) fp32.
__global__ void prep_kernel(const float4* __restrict__ h4, float4* __restrict__ out4,
                            const float* __restrict__ weight,
                            const float* __restrict__ w_comp,
                            ushort* __restrict__ WT2, int* __restrict__ cnt) {
    int gid = blockIdx.x * 256 + threadIdx.x;
    if (gid < NBIN + 8) cnt[gid] = 0;
    if (gid < WSZ) {
        int o = gid >> 10;
        int k = gid & 1023;
        int r = k >> 6;
        int d = k & 63;
        const float* wc = w_comp + (d & 15) * NBASE;
        const float* wv = weight + (size_t)(4 * r + (d >> 4)) * 512 + o;
        float acc = 0.f;
#pragma unroll
        for (int b = 0; b < NBASE; ++b)
            acc = fmaf(wc[b], wv[b * 64], acc);
        WT2[gid] = f2bf(acc);
    }
    if (gid < H4) {
        float4 v = h4[gid];
        v.x = fmaxf(v.x, 0.f); v.y = fmaxf(v.y, 0.f);
        v.z = fmaxf(v.z, 0.f); v.w = fmaxf(v.w, 0.f);
        out4[gid] = v;
    }
}

// Histogram over coarse dst bins (dst>>4).
__global__ void hist_kernel(const int* __restrict__ dst, int* __restrict__ cnt) {
    int stride = gridDim.x * blockDim.x;
    for (int i = blockIdx.x * blockDim.x + threadIdx.x; i < EE; i += stride)
        atomicAdd(&cnt[dst[i] >> 4], 1);
}

// Exclusive scan of 6250 bins: single block, 7 serial/thread + LDS Hillis-Steele.
// (Tiny data - 25 KB - unlike the round-4 400 KB 1-block mistake.)
__global__ __launch_bounds__(1024) void scan_kernel(const int* __restrict__ cnt,
                                                    int* __restrict__ off,
                                                    int* __restrict__ cur) {
    __shared__ int lds[1024];
    int t = threadIdx.x;
    int lo = t * 7, hi = lo + 7;
    if (lo > NBIN) lo = NBIN;
    if (hi > NBIN) hi = NBIN;
    int s = 0;
    for (int i = lo; i < hi; ++i) s += cnt[i];
    lds[t] = s;
    __syncthreads();
    for (int o = 1; o < 1024; o <<= 1) {
        int u = (t >= o) ? lds[t - o] : 0;
        __syncthreads();
        lds[t] += u;
        __syncthreads();
    }
    int base = (t > 0) ? lds[t - 1] : 0;
    for (int i = lo; i < hi; ++i) { off[i] = base; cur[i] = base; base += cnt[i]; }
    if (t == 1023) off[NBIN] = lds[1023];
}

// Bucket edges by dst>>4; payload packs (src, rel, dst&15) in 25 bits.
__global__ void scatter_kernel(const int* __restrict__ src, const int* __restrict__ dst,
                               const int* __restrict__ rel, int* __restrict__ cur,
                               int* __restrict__ pidx) {
    int i = blockIdx.x * blockDim.x + threadIdx.x;
    if (i < EE) {
        int d = dst[i];
        int pos = atomicAdd(&cur[d >> 4], 1);
        pidx[pos] = (src[i] << 8) | (rel[i] << 4) | (d & 15);
    }
}

// Fused input-aggregation + GEMM: one block per 16-dst tile.
// Phase A: S[ld][k=rel*64+d] += h[src][d] in LDS fp32 (ds_add_f32, lane=d;
//          h is 25.6 MB -> LLC-resident gather, NOT a 205 MB intermediate).
// Phase B: h2[tile] = bf16(S) @ WT2^T via MFMA, K=1024, written once, fp32.
// LDS = 16*1024 fp32 = 64 KB exactly (2 blocks/CU). No padding possible at
// the 64 KB limit, so banks fixed by XOR swizzle: kx = k ^ ((ld&7)<<2) —
// preserves 4-float contiguity (b128-able), spreads the row-strided Phase-B
// frag reads across 8 bank groups (2-way = free) and keeps Phase-A writes
// (lane=d) conflict-free.
__global__ __launch_bounds__(256) void rgcn_fused_kernel(
    const int* __restrict__ off, const int* __restrict__ pidx,
    const float* __restrict__ h, const ushort* __restrict__ WT2,
    float* __restrict__ h2) {
    __shared__ float S[16 * KDIM];   // 64 KB
    const int tid = threadIdx.x;
    const int lane = tid & 63;
    const int wvid = tid >> 6;
    for (int i = tid; i < 16 * KDIM; i += 256) S[i] = 0.f;
    __syncthreads();

    const int b = blockIdx.x;
    const int s = off[b], e = off[b + 1];

    // ---- Phase A: aggregate h rows into S (LDS fp32 atomics) ----
#pragma unroll 4
    for (int i = s + wvid; i < e; i += 4) {
        int p  = __builtin_amdgcn_readfirstlane(pidx[i]);
        int sn = p >> 8;
        int ld = p & 15;
        int k  = (((p >> 4) & 15) << 6) + lane;       // rel*64 + d
        float v = h[(size_t)sn * FDIM + lane];
        int idx = ld * KDIM + (k ^ ((ld & 7) << 2));  // swizzled
        __hip_atomic_fetch_add(&S[idx], v, __ATOMIC_RELAXED, __HIP_MEMORY_SCOPE_WORKGROUP);
    }
    __syncthreads();

    // ---- Phase B: 16x1024 @ 1024x64 GEMM, wave wvid owns o-tile [16w,16w+16) ----
    const int quad = lane >> 4, l15 = lane & 15;
    const int C = (l15 & 7) << 2;                      // row swizzle constant
    const float4* S4 = (const float4*)S;
    const short8* wrow = (const short8*)(WT2 + (size_t)(wvid * 16 + l15) * KDIM);
    f32x4 acc = (f32x4){0.f, 0.f, 0.f, 0.f};
#pragma unroll
    for (int ks = 0; ks < 32; ++ks) {
        int k0 = ks * 32 + quad * 8;
        float4 a = S4[l15 * 256 + ((k0 ^ C) >> 2)];
        float4 c = S4[l15 * 256 + (((k0 + 4) ^ C) >> 2)];
        short8 Afr;
        Afr[0] = (short)f2bf(a.x); Afr[1] = (short)f2bf(a.y);
        Afr[2] = (short)f2bf(a.z); Afr[3] = (short)f2bf(a.w);
        Afr[4] = (short)f2bf(c.x); Afr[5] = (short)f2bf(c.y);
        Afr[6] = (short)f2bf(c.z); Afr[7] = (short)f2bf(c.w);
        short8 Bfr = wrow[ks * 4 + quad];
        acc = __builtin_amdgcn_mfma_f32_16x16x32_bf16(Afr, Bfr, acc, 0, 0, 0);
    }
    // D layout: col=lane&15 -> o within tile, row=quad*4+reg -> local dst
    const int v0 = b * 16;
    const int ocol = wvid * 16 + l15;
#pragma unroll
    for (int r = 0; r < 4; ++r)
        h2[(size_t)(v0 + quad * 4 + r) * FDIM + ocol] = acc[r];
}

extern "C" void kernel_launch(void* const* d_in, const int* in_sizes, int n_in,
                              void* d_out, int out_size, void* d_ws, size_t ws_size,
                              hipStream_t stream) {
    const float* h      = (const float*)d_in[0];
    const float* weight = (const float*)d_in[1];
    const float* w_comp = (const float*)d_in[2];
    const int*   src    = (const int*)d_in[3];
    const int*   dst    = (const int*)d_in[4];
    const int*   rel    = (const int*)d_in[5];

    float* out_hnew = (float*)d_out;
    float* out_h2   = out_hnew + HN;

    char* ws = (char*)d_ws;
    // Workspace (~4.2 MB): WT2 128 KB | cnt | off | cur | pidx 4 MB
    ushort* WT2  = (ushort*)ws;
    int*    cnt  = (int*)(ws + 131072);
    int*    off  = (int*)(ws + 156160);
    int*    cur  = (int*)(ws + 181248);
    int*    pidx = (int*)(ws + 206336);

    hipLaunchKernelGGL(prep_kernel, dim3((H4 + 255) / 256), dim3(256), 0, stream,
                       (const float4*)h, (float4*)out_hnew, weight, w_comp, WT2, cnt);
    hipLaunchKernelGGL(hist_kernel, dim3(1024), dim3(256), 0, stream, dst, cnt);
    hipLaunchKernelGGL(scan_kernel, dim3(1), dim3(1024), 0, stream, cnt, off, cur);
    hipLaunchKernelGGL(scatter_kernel, dim3((EE + 255) / 256), dim3(256), 0, stream,
                       src, dst, rel, cur, pidx);
    hipLaunchKernelGGL(rgcn_fused_kernel, dim3(NBIN), dim3(256), 0, stream,
                       off, pidx, h, WT2, out_h2);
}